// Round 20
// baseline (252.191 us; speedup 1.0000x reference)
//
#include <hip/hip_runtime.h>
#include <hip/hip_bf16.h>

#define NPTS 131072
#define DIM  512
#define HID  128
#define KCL  3
#define NPOSI 8192
#define NNEGI 8192

typedef __attribute__((ext_vector_type(8))) short bf16x8;
typedef __attribute__((ext_vector_type(4))) float f32x4;

#define ASG __attribute__((address_space(1)))
#define ASL __attribute__((address_space(3)))

// ws layout (float offsets)
enum {
  WS_SHIFT_POS = 0,        // 512
  WS_SHIFT_NEG = 512,      // 512
  WS_NEGSUM    = 1024,     // 512
  WS_NEGPART   = 1536,     // 256*512 -> ends 132608
  WS_SUMS      = 132608,   // 4*1539 -> ends 138764
  WS_PPROTO    = 138764,   // 4*512 -> 140812
  WS_PN        = 140812,   // 4 -> 140816
  WS_W1FRAG    = 140816,   // 32768 -> 173584
  WS_CLSL      = 173584,   // 131072 -> 304656 floats (~1.22 MB)
};
#define SUMS_STRIDE 1539

__device__ __forceinline__ short f2bf(float x) {
  __hip_bfloat16 h = __float2bfloat16(x);
  return *reinterpret_cast<short*>(&h);
}

// ================= k_prep (R19-verbatim): W1 frag-swizzle | calib | negmean partials | zero sums =================
__global__ __launch_bounds__(256, 1) void k_prep(const float* __restrict__ W1,
                                                 const float* __restrict__ Wp, const float* __restrict__ bp,
                                                 const float* __restrict__ Wn, const float* __restrict__ bn,
                                                 const float* __restrict__ pos_ctx, const float* __restrict__ neg_ctx,
                                                 const float* __restrict__ zp, const int* __restrict__ neg_idx,
                                                 float* __restrict__ ws) {
  int bid = blockIdx.x, t = threadIdx.x;
  if (bid < 32) {
    int fid = bid * 256 + t;           // 0..8191
    int kc = fid >> 9;
    int n  = (fid >> 6) & 7;
    int l  = fid & 63;
    int row = n * 16 + (l & 15);
    int col = kc * 32 + (l >> 4) * 8;
    const float* src = W1 + (size_t)row * DIM + col;
    float4 v0 = *(const float4*)(src);
    float4 v1 = *(const float4*)(src + 4);
    bf16x8 f;
    f[0] = f2bf(v0.x); f[1] = f2bf(v0.y); f[2] = f2bf(v0.z); f[3] = f2bf(v0.w);
    f[4] = f2bf(v1.x); f[5] = f2bf(v1.y); f[6] = f2bf(v1.z); f[7] = f2bf(v1.w);
    ((bf16x8*)(ws + WS_W1FRAG))[fid] = f;
  } else if (bid < 64) {
    int b = bid - 32;
    int mat = b >> 4;
    const float* W    = mat ? Wn : Wp;
    const float* bias = mat ? bn : bp;
    const float* ctx  = mat ? neg_ctx : pos_ctx;
    float* outp = ws + (mat ? WS_SHIFT_NEG : WS_SHIFT_POS);
    int row = (b & 15) * 32 + (t >> 3);
    int sub = t & 7;
    const float* wr = W + row * DIM + sub * 64;
    const float* cr = ctx + sub * 64;
    float s = 0.f;
#pragma unroll
    for (int j = 0; j < 64; j += 4) {
      float4 w4 = *(const float4*)(wr + j);
      float4 c4 = *(const float4*)(cr + j);
      s += w4.x * c4.x + w4.y * c4.y + w4.z * c4.z + w4.w * c4.w;
    }
    s += __shfl_xor(s, 1);
    s += __shfl_xor(s, 2);
    s += __shfl_xor(s, 4);
    if (sub == 0) outp[row] = 0.15f * (s + bias[row]);
  } else if (bid < 320) {
    int jb = bid - 64;
    int c0 = t * 2;
    float a0 = 0.f, a1 = 0.f;
    int base = jb * 32;
#pragma unroll 8
    for (int jj = 0; jj < 32; ++jj) {
      int row = neg_idx[base + jj];
      float2 v = *(const float2*)(zp + (size_t)row * DIM + c0);
      a0 += v.x; a1 += v.y;
    }
    ws[WS_NEGPART + jb * DIM + c0]     = a0;
    ws[WS_NEGPART + jb * DIM + c0 + 1] = a1;
  } else {
    for (int idx = t; idx < 4 * SUMS_STRIDE; idx += 256) ws[WS_SUMS + idx] = 0.f;
  }
}

// ================= k_kmcls<IT> (R19-verbatim): km blocks + 2048 cls tiles =================
template <int IT>
__global__ __launch_bounds__(256, 4) void k_kmcls(const float* __restrict__ zp,
                                                  const int* __restrict__ pos_idx,
                                                  const float* __restrict__ zc,
                                                  const float* __restrict__ b1,
                                                  const float* __restrict__ W2,
                                                  const float* __restrict__ b2,
                                                  float* __restrict__ ws) {
  __shared__ __align__(16) float Abuf[16 * DIM];   // 32 KB union: cls tile | km cc+lsum
  __shared__ float cn4[KCL + 1];
  __shared__ float lcnt[KCL];
  __shared__ float clsv[16];

  int bid = blockIdx.x, t = threadIdx.x;
  int w = t >> 6, l = t & 63;

  if (bid == 256) {
    if (IT == 0) {
      int c0 = t * 2;
      float a0 = 0.f, a1 = 0.f;
#pragma unroll 8
      for (int j = 0; j < 256; ++j) {
        float2 v = *(const float2*)(ws + WS_NEGPART + j * DIM + c0);
        a0 += v.x; a1 += v.y;
      }
      ws[WS_NEGSUM + c0]     = a0;
      ws[WS_NEGSUM + c0 + 1] = a1;
    }
    return;
  }

  if (bid < 256) {
    float* cc   = Abuf;          // 1536 floats
    float* lsum = Abuf + 2048;   // 1536 floats

    for (int idx = t; idx < KCL * DIM; idx += 256) lsum[idx] = 0.f;
    if (t < KCL) lcnt[t] = 0.f;

    for (int idx = t; idx < KCL * DIM; idx += 256) {
      int k = idx >> 9;
      int sel = (k == 0) ? 0 : ((k == 1) ? 4095 : 8191);
      float v = zp[(size_t)pos_idx[sel] * DIM + (idx & 511)];
#pragma unroll
      for (int j = 0; j < IT; ++j) {
        float cntv = ws[WS_SUMS + j * SUMS_STRIDE + 3 * DIM + k];
        float sv   = ws[WS_SUMS + j * SUMS_STRIDE + idx];
        v = (cntv > 0.f) ? sv / cntv : v;
      }
      cc[idx] = v;
    }
    __syncthreads();
    if (w < KCL) {
      float s = 0.f;
#pragma unroll
      for (int m = 0; m < 8; ++m) { float v = cc[w * DIM + l + m * 64]; s += v * v; }
#pragma unroll
      for (int m = 1; m < 64; m <<= 1) s += __shfl_xor(s, m);
      if (l == 0) cn4[w] = s;
    }
    __syncthreads();

    float ck0[8], ck1[8], ck2[8];
#pragma unroll
    for (int j = 0; j < 8; ++j) {
      ck0[j] = cc[0 * DIM + l * 8 + j];
      ck1[j] = cc[1 * DIM + l * 8 + j];
      ck2[j] = cc[2 * DIM + l * 8 + j];
    }
    float cn0 = cn4[0], cn1 = cn4[1], cn2 = cn4[2];
    float acc0[8] = {0,0,0,0,0,0,0,0}, acc1[8] = {0,0,0,0,0,0,0,0}, acc2[8] = {0,0,0,0,0,0,0,0};
    float cnt0 = 0.f, cnt1 = 0.f, cnt2 = 0.f;

    int wid = bid * 4 + w;   // 1024 waves, 8 rows each (strided)
#pragma unroll 2
    for (int p = wid; p < NPOSI; p += 1024) {
      int row = pos_idx[p];
      const float* xr = zp + (size_t)row * DIM + l * 8;
      float4 x0 = *(const float4*)(xr);
      float4 x1 = *(const float4*)(xr + 4);
      float x[8] = {x0.x, x0.y, x0.z, x0.w, x1.x, x1.y, x1.z, x1.w};
      float d0 = 0.f, d1 = 0.f, d2 = 0.f;
#pragma unroll
      for (int j = 0; j < 8; ++j) { d0 += x[j] * ck0[j]; d1 += x[j] * ck1[j]; d2 += x[j] * ck2[j]; }
#pragma unroll
      for (int m = 1; m < 64; m <<= 1) {
        d0 += __shfl_xor(d0, m); d1 += __shfl_xor(d1, m); d2 += __shfl_xor(d2, m);
      }
      float t0 = cn0 - 2.f * d0, t1 = cn1 - 2.f * d1, t2 = cn2 - 2.f * d2;
      int a = 0; float best = t0;
      if (t1 < best) { best = t1; a = 1; }
      if (t2 < best) { best = t2; a = 2; }
      if (a == 0)      { cnt0 += 1.f;
#pragma unroll
        for (int j = 0; j < 8; ++j) acc0[j] += x[j]; }
      else if (a == 1) { cnt1 += 1.f;
#pragma unroll
        for (int j = 0; j < 8; ++j) acc1[j] += x[j]; }
      else             { cnt2 += 1.f;
#pragma unroll
        for (int j = 0; j < 8; ++j) acc2[j] += x[j]; }
    }
#pragma unroll
    for (int j = 0; j < 8; ++j) {
      atomicAdd(&lsum[0 * DIM + l * 8 + j], acc0[j]);
      atomicAdd(&lsum[1 * DIM + l * 8 + j], acc1[j]);
      atomicAdd(&lsum[2 * DIM + l * 8 + j], acc2[j]);
    }
    if (l == 0) {
      atomicAdd(&lcnt[0], cnt0); atomicAdd(&lcnt[1], cnt1); atomicAdd(&lcnt[2], cnt2);
    }
    __syncthreads();
    for (int idx = t; idx < KCL * DIM; idx += 256) atomicAdd(&ws[WS_SUMS + IT * SUMS_STRIDE + idx], lsum[idx]);
    if (t < KCL) atomicAdd(&ws[WS_SUMS + IT * SUMS_STRIDE + 3 * DIM + t], lcnt[t]);
    return;
  }

  // ---------------- cls tile (R19-verbatim body) ----------------
  {
    int c = bid - 257;                                  // 0..2047
    int tile = IT * 2048 + ((c & 7) * 256 + (c >> 3));  // XCD swizzle within chunk
    int i0 = tile * 16;
    float* Azc = Abuf;

    const float* gsrc = zc + (size_t)(i0 + w * 4) * DIM;
#pragma unroll
    for (int r = 0; r < 4; ++r) {
      int rloc = w * 4 + r;
      int swz = (rloc & 7) << 2;
#pragma unroll
      for (int seg = 0; seg < 2; ++seg) {
        int cc2 = seg * 256 + ((l * 4) ^ swz);
        __builtin_amdgcn_global_load_lds((const ASG void*)(gsrc + (size_t)r * DIM + cc2),
                                         (ASL void*)&Azc[rloc * DIM + seg * 256], 16, 0, 0);
      }
    }
    if (t < 16) clsv[t] = 0.f;
    int col_l = l & 15;
    float b1c[2], w2c[2];
#pragma unroll
    for (int nn = 0; nn < 2; ++nn) {
      int col = (w * 2 + nn) * 16 + col_l;
      b1c[nn] = b1[col];
      w2c[nn] = W2[col];
    }
    float b2v = b2[0];
    __syncthreads();   // single drain

    const bf16x8* w1f = (const bf16x8*)(ws + WS_W1FRAG);
    int sub = l >> 4, arow = l & 15;
    int swz = (arow & 7) << 2;
    int abase = arow * DIM;
    f32x4 acc[2];
    acc[0] = (f32x4){0.f, 0.f, 0.f, 0.f};
    acc[1] = (f32x4){0.f, 0.f, 0.f, 0.f};
    bf16x8 B2[3][2];
#pragma unroll
    for (int pf = 0; pf < 3; ++pf)
#pragma unroll
      for (int nn = 0; nn < 2; ++nn)
        B2[pf][nn] = w1f[pf * 512 + (w * 2 + nn) * 64 + l];

#pragma unroll
    for (int kc = 0; kc < 16; ++kc) {
      int g = kc * 32 + sub * 8;
      float4 a0 = *(const float4*)&Azc[abase + (g ^ swz)];
      float4 a1 = *(const float4*)&Azc[abase + ((g + 4) ^ swz)];
      if (kc + 3 < 16) {
#pragma unroll
        for (int nn = 0; nn < 2; ++nn)
          B2[kc % 3][nn] = w1f[(kc + 3) * 512 + (w * 2 + nn) * 64 + l];
      }
      bf16x8 af;
      af[0] = f2bf(a0.x); af[1] = f2bf(a0.y); af[2] = f2bf(a0.z); af[3] = f2bf(a0.w);
      af[4] = f2bf(a1.x); af[5] = f2bf(a1.y); af[6] = f2bf(a1.z); af[7] = f2bf(a1.w);
#pragma unroll
      for (int nn = 0; nn < 2; ++nn)
        acc[nn] = __builtin_amdgcn_mfma_f32_16x16x32_bf16(af, B2[kc % 3][nn], acc[nn], 0, 0, 0);
    }
    float prt[4] = {0.f, 0.f, 0.f, 0.f};
#pragma unroll
    for (int nn = 0; nn < 2; ++nn) {
#pragma unroll
      for (int r = 0; r < 4; ++r) {
        float h = acc[nn][r] + b1c[nn];
        h = h > 0.f ? h : 0.f;
        prt[r] += h * w2c[nn];
      }
    }
#pragma unroll
    for (int m = 1; m < 16; m <<= 1) {
#pragma unroll
      for (int r = 0; r < 4; ++r) prt[r] += __shfl_xor(prt[r], m);
    }
    if (col_l == 0) {
      float add = (w == 0) ? b2v : 0.f;
#pragma unroll
      for (int r = 0; r < 4; ++r)
        atomicAdd(&clsv[sub * 4 + r], prt[r] + add);
    }
    __syncthreads();
    if (t < 16) ws[WS_CLSL + i0 + t] = clsv[t];
  }
}

// ================= k_fin (R19-verbatim): finalize prototypes + norms once =================
__global__ __launch_bounds__(256) void k_fin(const float* __restrict__ zp,
                                             const int* __restrict__ pos_idx,
                                             float* __restrict__ ws, float* __restrict__ out) {
  __shared__ __align__(16) float pp[4 * DIM];
  int t = threadIdx.x, w = t >> 6, l = t & 63;
  for (int idx = t; idx < KCL * DIM; idx += 256) {
    int k = idx >> 9, d = idx & 511;
    int sel = (k == 0) ? 0 : ((k == 1) ? 4095 : 8191);
    float v = zp[(size_t)pos_idx[sel] * DIM + d];
#pragma unroll
    for (int j = 0; j < 4; ++j) {
      float cntv = ws[WS_SUMS + j * SUMS_STRIDE + 3 * DIM + k];
      float sv   = ws[WS_SUMS + j * SUMS_STRIDE + idx];
      v = (cntv > 0.f) ? sv / cntv : v;
    }
    pp[idx] = v + ws[WS_SHIFT_POS + d];
  }
  for (int d = t; d < DIM; d += 256)
    pp[3 * DIM + d] = ws[WS_NEGSUM + d] * (1.f / NNEGI) + ws[WS_SHIFT_NEG + d];
  __syncthreads();
  {
    float s = 0.f;
#pragma unroll
    for (int m = 0; m < 8; ++m) { float v = pp[w * DIM + l + m * 64]; s += v * v; }
#pragma unroll
    for (int m = 1; m < 64; m <<= 1) s += __shfl_xor(s, m);
    if (l == 0) ws[WS_PN + w] = s;
  }
  for (int idx = t; idx < 4 * DIM; idx += 256) {
    ws[WS_PPROTO + idx] = pp[idx];
    out[7 * NPTS + idx] = pp[idx];
  }
}

// ================= k_proto: protos read direct from L2 ws -> LDS 32 KB, 4+ blocks/CU =================
__global__ __launch_bounds__(256, 4) void k_proto(const float* __restrict__ zp,
                                                  const float* __restrict__ ws,
                                                  float* __restrict__ out) {
  __shared__ __align__(16) float Azp[16 * DIM];   // 32 KB (only LDS)

  int t = threadIdx.x, w = t >> 6, l = t & 63;
  int bid = (blockIdx.x & 7) * 1024 + (blockIdx.x >> 3);  // bijective XCD swizzle
  int i0 = bid * 16;

  {
    const float* gsrc = zp + (size_t)(i0 + w * 4) * DIM;
#pragma unroll
    for (int r = 0; r < 4; ++r) {
      int rloc = w * 4 + r;
      int swz = (rloc & 7) << 2;
#pragma unroll
      for (int seg = 0; seg < 2; ++seg) {
        int c = seg * 256 + ((l * 4) ^ swz);
        __builtin_amdgcn_global_load_lds((const ASG void*)(gsrc + (size_t)r * DIM + c),
                                         (ASL void*)&Azp[rloc * DIM + seg * 256], 16, 0, 0);
      }
    }
  }
  __syncthreads();   // single drain

  const float* wpp = ws + WS_PPROTO;   // L2/L3-resident 8 KB
  int s = l & 15, r4 = l >> 4;
  int rloc = w * 4 + r4;
  int swz = (rloc & 7) << 2;
  int xbase = rloc * DIM;
  float d0 = 0.f, d1 = 0.f, d2 = 0.f, dn = 0.f, sx = 0.f;
#pragma unroll
  for (int j = 0; j < 8; ++j) {
    int c = j * 64 + s * 4;
    float4 x  = *(const float4*)&Azp[xbase + (c ^ swz)];
    float4 c0 = *(const float4*)&wpp[0 * DIM + c];
    float4 c1 = *(const float4*)&wpp[1 * DIM + c];
    float4 c2 = *(const float4*)&wpp[2 * DIM + c];
    float4 c3 = *(const float4*)&wpp[3 * DIM + c];
    d0 += x.x * c0.x + x.y * c0.y + x.z * c0.z + x.w * c0.w;
    d1 += x.x * c1.x + x.y * c1.y + x.z * c1.z + x.w * c1.w;
    d2 += x.x * c2.x + x.y * c2.y + x.z * c2.z + x.w * c2.w;
    dn += x.x * c3.x + x.y * c3.y + x.z * c3.z + x.w * c3.w;
    sx += x.x * x.x  + x.y * x.y  + x.z * x.z  + x.w * x.w;
  }
#pragma unroll
  for (int m = 1; m < 16; m <<= 1) {
    d0 += __shfl_xor(d0, m);
    d1 += __shfl_xor(d1, m);
    d2 += __shfl_xor(d2, m);
    dn += __shfl_xor(dn, m);
    sx += __shfl_xor(sx, m);
  }
  if (s == 0) {
    int i = i0 + rloc;
    float pn0 = ws[WS_PN + 0], pn1 = ws[WS_PN + 1], pn2 = ws[WS_PN + 2], nn = ws[WS_PN + 3];
    float e0 = sx + pn0 - 2.f * d0; e0 = fmaxf(e0, 0.f);
    float e1 = sx + pn1 - 2.f * d1; e1 = fmaxf(e1, 0.f);
    float e2 = sx + pn2 - 2.f * d2; e2 = fmaxf(e2, 0.f);
    float dpos = e0; int a = 0;
    if (e1 < dpos) { dpos = e1; a = 1; }
    if (e2 < dpos) { dpos = e2; a = 2; }
    float dneg = (sx + nn - 2.f * dn) * (1.f / DIM);
    float plog = (dneg - dpos) * 0.04419417382415922f;   // 1/sqrt(512)
    float o2 = 0.2f * plog;
    float lg = (ws[WS_CLSL + i] + o2) * 0.4f;            // /2.5
    float prob = 1.f / (1.f + expf(-lg));
    out[i]            = lg;
    out[NPTS + i]     = prob;
    out[2 * NPTS + i] = o2;
    out[3 * NPTS + i] = (float)a;
    out[4 * NPTS + 3 * i]     = e0;
    out[4 * NPTS + 3 * i + 1] = e1;
    out[4 * NPTS + 3 * i + 2] = e2;
  }
}

extern "C" void kernel_launch(void* const* d_in, const int* in_sizes, int n_in,
                              void* d_out, int out_size, void* d_ws, size_t ws_size,
                              hipStream_t stream) {
  const float* z_cls   = (const float*)d_in[0];
  const float* z_proto = (const float*)d_in[1];
  const float* pos_ctx = (const float*)d_in[2];
  const float* neg_ctx = (const float*)d_in[3];
  const float* W1      = (const float*)d_in[4];
  const float* b1      = (const float*)d_in[5];
  const float* W2      = (const float*)d_in[6];
  const float* b2      = (const float*)d_in[7];
  const float* Wp      = (const float*)d_in[8];
  const float* bp      = (const float*)d_in[9];
  const float* Wn      = (const float*)d_in[10];
  const float* bn      = (const float*)d_in[11];
  const int* pos_idx   = (const int*)d_in[12];
  const int* neg_idx   = (const int*)d_in[13];
  float* out           = (float*)d_out;
  float* ws            = (float*)d_ws;

  k_prep<<<321, 256, 0, stream>>>(W1, Wp, bp, Wn, bn, pos_ctx, neg_ctx, z_proto, neg_idx, ws);
  k_kmcls<0><<<2305, 256, 0, stream>>>(z_proto, pos_idx, z_cls, b1, W2, b2, ws);
  k_kmcls<1><<<2305, 256, 0, stream>>>(z_proto, pos_idx, z_cls, b1, W2, b2, ws);
  k_kmcls<2><<<2305, 256, 0, stream>>>(z_proto, pos_idx, z_cls, b1, W2, b2, ws);
  k_kmcls<3><<<2305, 256, 0, stream>>>(z_proto, pos_idx, z_cls, b1, W2, b2, ws);
  k_fin<<<1, 256, 0, stream>>>(z_proto, pos_idx, ws, out);
  k_proto<<<NPTS / 16, 256, 0, stream>>>(z_proto, ws, out);
}

// Round 21
// 242.463 us; speedup vs baseline: 1.0401x; 1.0401x over previous
//
#include <hip/hip_runtime.h>
#include <hip/hip_bf16.h>

#define NPTS 131072
#define DIM  512
#define HID  128
#define KCL  3
#define NPOSI 8192
#define NNEGI 8192

typedef __attribute__((ext_vector_type(8))) short bf16x8;
typedef __attribute__((ext_vector_type(4))) float f32x4;

#define ASG __attribute__((address_space(1)))
#define ASL __attribute__((address_space(3)))

// ws layout (float offsets)
enum {
  WS_SHIFT_POS = 0,        // 512
  WS_SHIFT_NEG = 512,      // 512
  WS_NEGSUM    = 1024,     // 512
  WS_NEGPART   = 1536,     // 256*512 -> ends 132608
  WS_SUMS      = 132608,   // 4*1539 -> ends 138764
  WS_PPROTO    = 138764,   // 4*512 -> 140812
  WS_PN        = 140812,   // 4 -> 140816
  WS_W1FRAG    = 140816,   // 32768 -> 173584
  WS_CLSL      = 173584,   // 131072 -> 304656 floats (~1.22 MB)
};
#define SUMS_STRIDE 1539

__device__ __forceinline__ short f2bf(float x) {
  __hip_bfloat16 h = __float2bfloat16(x);
  return *reinterpret_cast<short*>(&h);
}

// ================= k_prep: W1 frag-swizzle | calib | negmean partials | zero sums =================
__global__ __launch_bounds__(256, 1) void k_prep(const float* __restrict__ W1,
                                                 const float* __restrict__ Wp, const float* __restrict__ bp,
                                                 const float* __restrict__ Wn, const float* __restrict__ bn,
                                                 const float* __restrict__ pos_ctx, const float* __restrict__ neg_ctx,
                                                 const float* __restrict__ zp, const int* __restrict__ neg_idx,
                                                 float* __restrict__ ws) {
  int bid = blockIdx.x, t = threadIdx.x;
  if (bid < 32) {
    int fid = bid * 256 + t;           // 0..8191
    int kc = fid >> 9;
    int n  = (fid >> 6) & 7;
    int l  = fid & 63;
    int row = n * 16 + (l & 15);
    int col = kc * 32 + (l >> 4) * 8;
    const float* src = W1 + (size_t)row * DIM + col;
    float4 v0 = *(const float4*)(src);
    float4 v1 = *(const float4*)(src + 4);
    bf16x8 f;
    f[0] = f2bf(v0.x); f[1] = f2bf(v0.y); f[2] = f2bf(v0.z); f[3] = f2bf(v0.w);
    f[4] = f2bf(v1.x); f[5] = f2bf(v1.y); f[6] = f2bf(v1.z); f[7] = f2bf(v1.w);
    ((bf16x8*)(ws + WS_W1FRAG))[fid] = f;
  } else if (bid < 64) {
    int b = bid - 32;
    int mat = b >> 4;
    const float* W    = mat ? Wn : Wp;
    const float* bias = mat ? bn : bp;
    const float* ctx  = mat ? neg_ctx : pos_ctx;
    float* outp = ws + (mat ? WS_SHIFT_NEG : WS_SHIFT_POS);
    int row = (b & 15) * 32 + (t >> 3);
    int sub = t & 7;
    const float* wr = W + row * DIM + sub * 64;
    const float* cr = ctx + sub * 64;
    float s = 0.f;
#pragma unroll
    for (int j = 0; j < 64; j += 4) {
      float4 w4 = *(const float4*)(wr + j);
      float4 c4 = *(const float4*)(cr + j);
      s += w4.x * c4.x + w4.y * c4.y + w4.z * c4.z + w4.w * c4.w;
    }
    s += __shfl_xor(s, 1);
    s += __shfl_xor(s, 2);
    s += __shfl_xor(s, 4);
    if (sub == 0) outp[row] = 0.15f * (s + bias[row]);
  } else if (bid < 320) {
    int jb = bid - 64;
    int c0 = t * 2;
    float a0 = 0.f, a1 = 0.f;
    int base = jb * 32;
#pragma unroll 8
    for (int jj = 0; jj < 32; ++jj) {
      int row = neg_idx[base + jj];
      float2 v = *(const float2*)(zp + (size_t)row * DIM + c0);
      a0 += v.x; a1 += v.y;
    }
    ws[WS_NEGPART + jb * DIM + c0]     = a0;
    ws[WS_NEGPART + jb * DIM + c0 + 1] = a1;
  } else {
    for (int idx = t; idx < 4 * SUMS_STRIDE; idx += 256) ws[WS_SUMS + idx] = 0.f;
  }
}

// ================= k_kmcls<IT>: km blocks (bid<257) + 2048 cls tiles (bid>=257) =================
template <int IT>
__global__ __launch_bounds__(256, 4) void k_kmcls(const float* __restrict__ zp,
                                                  const int* __restrict__ pos_idx,
                                                  const float* __restrict__ zc,
                                                  const float* __restrict__ b1,
                                                  const float* __restrict__ W2,
                                                  const float* __restrict__ b2,
                                                  float* __restrict__ ws) {
  __shared__ __align__(16) float Abuf[16 * DIM];   // 32 KB union: cls tile | km cc+lsum
  __shared__ float cn4[KCL + 1];
  __shared__ float lcnt[KCL];
  __shared__ float clsv[16];

  int bid = blockIdx.x, t = threadIdx.x;
  int w = t >> 6, l = t & 63;

  if (bid == 256) {
    if (IT == 0) {
      int c0 = t * 2;
      float a0 = 0.f, a1 = 0.f;
#pragma unroll 8
      for (int j = 0; j < 256; ++j) {
        float2 v = *(const float2*)(ws + WS_NEGPART + j * DIM + c0);
        a0 += v.x; a1 += v.y;
      }
      ws[WS_NEGSUM + c0]     = a0;
      ws[WS_NEGSUM + c0 + 1] = a1;
    }
    return;
  }

  if (bid < 256) {
    // ---------------- km assign ----------------
    float* cc   = Abuf;          // 1536 floats
    float* lsum = Abuf + 2048;   // 1536 floats

    for (int idx = t; idx < KCL * DIM; idx += 256) lsum[idx] = 0.f;
    if (t < KCL) lcnt[t] = 0.f;

    for (int idx = t; idx < KCL * DIM; idx += 256) {
      int k = idx >> 9;
      int sel = (k == 0) ? 0 : ((k == 1) ? 4095 : 8191);
      float v = zp[(size_t)pos_idx[sel] * DIM + (idx & 511)];
#pragma unroll
      for (int j = 0; j < IT; ++j) {
        float cntv = ws[WS_SUMS + j * SUMS_STRIDE + 3 * DIM + k];
        float sv   = ws[WS_SUMS + j * SUMS_STRIDE + idx];
        v = (cntv > 0.f) ? sv / cntv : v;
      }
      cc[idx] = v;
    }
    __syncthreads();
    if (w < KCL) {
      float s = 0.f;
#pragma unroll
      for (int m = 0; m < 8; ++m) { float v = cc[w * DIM + l + m * 64]; s += v * v; }
#pragma unroll
      for (int m = 1; m < 64; m <<= 1) s += __shfl_xor(s, m);
      if (l == 0) cn4[w] = s;
    }
    __syncthreads();

    float ck0[8], ck1[8], ck2[8];
#pragma unroll
    for (int j = 0; j < 8; ++j) {
      ck0[j] = cc[0 * DIM + l * 8 + j];
      ck1[j] = cc[1 * DIM + l * 8 + j];
      ck2[j] = cc[2 * DIM + l * 8 + j];
    }
    float cn0 = cn4[0], cn1 = cn4[1], cn2 = cn4[2];
    float acc0[8] = {0,0,0,0,0,0,0,0}, acc1[8] = {0,0,0,0,0,0,0,0}, acc2[8] = {0,0,0,0,0,0,0,0};
    float cnt0 = 0.f, cnt1 = 0.f, cnt2 = 0.f;

    int wid = bid * 4 + w;   // 1024 waves, 8 rows each (strided)
#pragma unroll 2
    for (int p = wid; p < NPOSI; p += 1024) {
      int row = pos_idx[p];
      const float* xr = zp + (size_t)row * DIM + l * 8;
      float4 x0 = *(const float4*)(xr);
      float4 x1 = *(const float4*)(xr + 4);
      float x[8] = {x0.x, x0.y, x0.z, x0.w, x1.x, x1.y, x1.z, x1.w};
      float d0 = 0.f, d1 = 0.f, d2 = 0.f;
#pragma unroll
      for (int j = 0; j < 8; ++j) { d0 += x[j] * ck0[j]; d1 += x[j] * ck1[j]; d2 += x[j] * ck2[j]; }
#pragma unroll
      for (int m = 1; m < 64; m <<= 1) {
        d0 += __shfl_xor(d0, m); d1 += __shfl_xor(d1, m); d2 += __shfl_xor(d2, m);
      }
      float t0 = cn0 - 2.f * d0, t1 = cn1 - 2.f * d1, t2 = cn2 - 2.f * d2;
      int a = 0; float best = t0;
      if (t1 < best) { best = t1; a = 1; }
      if (t2 < best) { best = t2; a = 2; }
      if (a == 0)      { cnt0 += 1.f;
#pragma unroll
        for (int j = 0; j < 8; ++j) acc0[j] += x[j]; }
      else if (a == 1) { cnt1 += 1.f;
#pragma unroll
        for (int j = 0; j < 8; ++j) acc1[j] += x[j]; }
      else             { cnt2 += 1.f;
#pragma unroll
        for (int j = 0; j < 8; ++j) acc2[j] += x[j]; }
    }
#pragma unroll
    for (int j = 0; j < 8; ++j) {
      atomicAdd(&lsum[0 * DIM + l * 8 + j], acc0[j]);
      atomicAdd(&lsum[1 * DIM + l * 8 + j], acc1[j]);
      atomicAdd(&lsum[2 * DIM + l * 8 + j], acc2[j]);
    }
    if (l == 0) {
      atomicAdd(&lcnt[0], cnt0); atomicAdd(&lcnt[1], cnt1); atomicAdd(&lcnt[2], cnt2);
    }
    __syncthreads();
    for (int idx = t; idx < KCL * DIM; idx += 256) atomicAdd(&ws[WS_SUMS + IT * SUMS_STRIDE + idx], lsum[idx]);
    if (t < KCL) atomicAdd(&ws[WS_SUMS + IT * SUMS_STRIDE + 3 * DIM + t], lcnt[t]);
    return;
  }

  // ---------------- cls tile ----------------
  {
    int c = bid - 257;                                  // 0..2047
    int tile = IT * 2048 + ((c & 7) * 256 + (c >> 3));  // XCD swizzle within chunk
    int i0 = tile * 16;
    float* Azc = Abuf;

    const float* gsrc = zc + (size_t)(i0 + w * 4) * DIM;
#pragma unroll
    for (int r = 0; r < 4; ++r) {
      int rloc = w * 4 + r;
      int swz = (rloc & 7) << 2;
#pragma unroll
      for (int seg = 0; seg < 2; ++seg) {
        int cc2 = seg * 256 + ((l * 4) ^ swz);
        __builtin_amdgcn_global_load_lds((const ASG void*)(gsrc + (size_t)r * DIM + cc2),
                                         (ASL void*)&Azc[rloc * DIM + seg * 256], 16, 0, 0);
      }
    }
    if (t < 16) clsv[t] = 0.f;
    int col_l = l & 15;
    float b1c[2], w2c[2];
#pragma unroll
    for (int nn = 0; nn < 2; ++nn) {
      int col = (w * 2 + nn) * 16 + col_l;
      b1c[nn] = b1[col];
      w2c[nn] = W2[col];
    }
    float b2v = b2[0];
    __syncthreads();   // single drain

    const bf16x8* w1f = (const bf16x8*)(ws + WS_W1FRAG);
    int sub = l >> 4, arow = l & 15;
    int swz = (arow & 7) << 2;
    int abase = arow * DIM;
    f32x4 acc[2];
    acc[0] = (f32x4){0.f, 0.f, 0.f, 0.f};
    acc[1] = (f32x4){0.f, 0.f, 0.f, 0.f};
    bf16x8 B2[3][2];
#pragma unroll
    for (int pf = 0; pf < 3; ++pf)
#pragma unroll
      for (int nn = 0; nn < 2; ++nn)
        B2[pf][nn] = w1f[pf * 512 + (w * 2 + nn) * 64 + l];

#pragma unroll
    for (int kc = 0; kc < 16; ++kc) {
      int g = kc * 32 + sub * 8;
      float4 a0 = *(const float4*)&Azc[abase + (g ^ swz)];
      float4 a1 = *(const float4*)&Azc[abase + ((g + 4) ^ swz)];
      if (kc + 3 < 16) {
#pragma unroll
        for (int nn = 0; nn < 2; ++nn)
          B2[kc % 3][nn] = w1f[(kc + 3) * 512 + (w * 2 + nn) * 64 + l];
      }
      bf16x8 af;
      af[0] = f2bf(a0.x); af[1] = f2bf(a0.y); af[2] = f2bf(a0.z); af[3] = f2bf(a0.w);
      af[4] = f2bf(a1.x); af[5] = f2bf(a1.y); af[6] = f2bf(a1.z); af[7] = f2bf(a1.w);
#pragma unroll
      for (int nn = 0; nn < 2; ++nn)
        acc[nn] = __builtin_amdgcn_mfma_f32_16x16x32_bf16(af, B2[kc % 3][nn], acc[nn], 0, 0, 0);
    }
    float prt[4] = {0.f, 0.f, 0.f, 0.f};
#pragma unroll
    for (int nn = 0; nn < 2; ++nn) {
#pragma unroll
      for (int r = 0; r < 4; ++r) {
        float h = acc[nn][r] + b1c[nn];
        h = h > 0.f ? h : 0.f;
        prt[r] += h * w2c[nn];
      }
    }
#pragma unroll
    for (int m = 1; m < 16; m <<= 1) {
#pragma unroll
      for (int r = 0; r < 4; ++r) prt[r] += __shfl_xor(prt[r], m);
    }
    if (col_l == 0) {
      float add = (w == 0) ? b2v : 0.f;
#pragma unroll
      for (int r = 0; r < 4; ++r)
        atomicAdd(&clsv[sub * 4 + r], prt[r] + add);
    }
    __syncthreads();
    if (t < 16) ws[WS_CLSL + i0 + t] = clsv[t];
  }
}

// ================= k_fin: finalize prototypes + norms once =================
__global__ __launch_bounds__(256) void k_fin(const float* __restrict__ zp,
                                             const int* __restrict__ pos_idx,
                                             float* __restrict__ ws, float* __restrict__ out) {
  __shared__ __align__(16) float pp[4 * DIM];
  int t = threadIdx.x, w = t >> 6, l = t & 63;
  for (int idx = t; idx < KCL * DIM; idx += 256) {
    int k = idx >> 9, d = idx & 511;
    int sel = (k == 0) ? 0 : ((k == 1) ? 4095 : 8191);
    float v = zp[(size_t)pos_idx[sel] * DIM + d];
#pragma unroll
    for (int j = 0; j < 4; ++j) {
      float cntv = ws[WS_SUMS + j * SUMS_STRIDE + 3 * DIM + k];
      float sv   = ws[WS_SUMS + j * SUMS_STRIDE + idx];
      v = (cntv > 0.f) ? sv / cntv : v;
    }
    pp[idx] = v + ws[WS_SHIFT_POS + d];
  }
  for (int d = t; d < DIM; d += 256)
    pp[3 * DIM + d] = ws[WS_NEGSUM + d] * (1.f / NNEGI) + ws[WS_SHIFT_NEG + d];
  __syncthreads();
  {
    float s = 0.f;
#pragma unroll
    for (int m = 0; m < 8; ++m) { float v = pp[w * DIM + l + m * 64]; s += v * v; }
#pragma unroll
    for (int m = 1; m < 64; m <<= 1) s += __shfl_xor(s, m);
    if (l == 0) ws[WS_PN + w] = s;
  }
  for (int idx = t; idx < 4 * DIM; idx += 256) {
    ws[WS_PPROTO + idx] = pp[idx];
    out[7 * NPTS + idx] = pp[idx];
  }
}

// ================= k_proto: 16-row tile, pp LDS-staged, single drain, 3 blocks/CU =================
__global__ __launch_bounds__(256, 3) void k_proto(const float* __restrict__ zp,
                                                  const float* __restrict__ ws,
                                                  float* __restrict__ out) {
  __shared__ __align__(16) float Azp[16 * DIM];   // 32 KB
  __shared__ __align__(16) float pp[4 * DIM];     // 8 KB
  __shared__ float pns[4];

  int t = threadIdx.x, w = t >> 6, l = t & 63;
  int bid = (blockIdx.x & 7) * 1024 + (blockIdx.x >> 3);  // bijective XCD swizzle
  int i0 = bid * 16;

  {
    const float* gsrc = zp + (size_t)(i0 + w * 4) * DIM;
#pragma unroll
    for (int r = 0; r < 4; ++r) {
      int rloc = w * 4 + r;
      int swz = (rloc & 7) << 2;
#pragma unroll
      for (int seg = 0; seg < 2; ++seg) {
        int c = seg * 256 + ((l * 4) ^ swz);
        __builtin_amdgcn_global_load_lds((const ASG void*)(gsrc + (size_t)r * DIM + c),
                                         (ASL void*)&Azp[rloc * DIM + seg * 256], 16, 0, 0);
      }
    }
  }
  for (int idx = t; idx < 512; idx += 256)
    ((float4*)pp)[idx] = ((const float4*)(ws + WS_PPROTO))[idx];
  if (t < 4) pns[t] = ws[WS_PN + t];
  __syncthreads();   // single drain

  int s = l & 15, r4 = l >> 4;
  int rloc = w * 4 + r4;
  int swz = (rloc & 7) << 2;
  int xbase = rloc * DIM;
  float d0 = 0.f, d1 = 0.f, d2 = 0.f, dn = 0.f, sx = 0.f;
#pragma unroll
  for (int j = 0; j < 8; ++j) {
    int c = j * 64 + s * 4;
    float4 x  = *(const float4*)&Azp[xbase + (c ^ swz)];
    float4 c0 = *(const float4*)&pp[0 * DIM + c];
    float4 c1 = *(const float4*)&pp[1 * DIM + c];
    float4 c2 = *(const float4*)&pp[2 * DIM + c];
    float4 c3 = *(const float4*)&pp[3 * DIM + c];
    d0 += x.x * c0.x + x.y * c0.y + x.z * c0.z + x.w * c0.w;
    d1 += x.x * c1.x + x.y * c1.y + x.z * c1.z + x.w * c1.w;
    d2 += x.x * c2.x + x.y * c2.y + x.z * c2.z + x.w * c2.w;
    dn += x.x * c3.x + x.y * c3.y + x.z * c3.z + x.w * c3.w;
    sx += x.x * x.x  + x.y * x.y  + x.z * x.z  + x.w * x.w;
  }
#pragma unroll
  for (int m = 1; m < 16; m <<= 1) {
    d0 += __shfl_xor(d0, m);
    d1 += __shfl_xor(d1, m);
    d2 += __shfl_xor(d2, m);
    dn += __shfl_xor(dn, m);
    sx += __shfl_xor(sx, m);
  }
  if (s == 0) {
    int i = i0 + rloc;
    float e0 = sx + pns[0] - 2.f * d0; e0 = fmaxf(e0, 0.f);
    float e1 = sx + pns[1] - 2.f * d1; e1 = fmaxf(e1, 0.f);
    float e2 = sx + pns[2] - 2.f * d2; e2 = fmaxf(e2, 0.f);
    float dpos = e0; int a = 0;
    if (e1 < dpos) { dpos = e1; a = 1; }
    if (e2 < dpos) { dpos = e2; a = 2; }
    float dneg = (sx + pns[3] - 2.f * dn) * (1.f / DIM);
    float plog = (dneg - dpos) * 0.04419417382415922f;   // 1/sqrt(512)
    float o2 = 0.2f * plog;
    float lg = (ws[WS_CLSL + i] + o2) * 0.4f;            // /2.5
    float prob = 1.f / (1.f + expf(-lg));
    out[i]            = lg;
    out[NPTS + i]     = prob;
    out[2 * NPTS + i] = o2;
    out[3 * NPTS + i] = (float)a;
    out[4 * NPTS + 3 * i]     = e0;
    out[4 * NPTS + 3 * i + 1] = e1;
    out[4 * NPTS + 3 * i + 2] = e2;
  }
}

extern "C" void kernel_launch(void* const* d_in, const int* in_sizes, int n_in,
                              void* d_out, int out_size, void* d_ws, size_t ws_size,
                              hipStream_t stream) {
  const float* z_cls   = (const float*)d_in[0];
  const float* z_proto = (const float*)d_in[1];
  const float* pos_ctx = (const float*)d_in[2];
  const float* neg_ctx = (const float*)d_in[3];
  const float* W1      = (const float*)d_in[4];
  const float* b1      = (const float*)d_in[5];
  const float* W2      = (const float*)d_in[6];
  const float* b2      = (const float*)d_in[7];
  const float* Wp      = (const float*)d_in[8];
  const float* bp      = (const float*)d_in[9];
  const float* Wn      = (const float*)d_in[10];
  const float* bn      = (const float*)d_in[11];
  const int* pos_idx   = (const int*)d_in[12];
  const int* neg_idx   = (const int*)d_in[13];
  float* out           = (float*)d_out;
  float* ws            = (float*)d_ws;

  k_prep<<<321, 256, 0, stream>>>(W1, Wp, bp, Wn, bn, pos_ctx, neg_ctx, z_proto, neg_idx, ws);
  k_kmcls<0><<<2305, 256, 0, stream>>>(z_proto, pos_idx, z_cls, b1, W2, b2, ws);
  k_kmcls<1><<<2305, 256, 0, stream>>>(z_proto, pos_idx, z_cls, b1, W2, b2, ws);
  k_kmcls<2><<<2305, 256, 0, stream>>>(z_proto, pos_idx, z_cls, b1, W2, b2, ws);
  k_kmcls<3><<<2305, 256, 0, stream>>>(z_proto, pos_idx, z_cls, b1, W2, b2, ws);
  k_fin<<<1, 256, 0, stream>>>(z_proto, pos_idx, ws, out);
  k_proto<<<NPTS / 16, 256, 0, stream>>>(z_proto, ws, out);
}